// Round 1
// baseline (105.393 us; speedup 1.0000x reference)
//
#include <hip/hip_runtime.h>

#define CV_H 96
#define CV_W 128
#define CV_C 16
#define CV_K 7
#define CV_D 64
#define CV_EPS 1e-8f

// ---------------------------------------------------------------------------
// Setup: depth planes (log-spaced) + per-view fused projection matrices.
// M[k] = [ A (3x3 row-major) | b (3) ] with A = (Ks@E)[:3,:3] @ invK[:3,:3],
// b = (Ks@E)[:3,3].  cam = depth * (A @ [x+.5, y+.5, 1]) + b.
// ---------------------------------------------------------------------------
__global__ void cv_setup(const float* __restrict__ extr,
                         const float* __restrict__ Ks,
                         const float* __restrict__ invK,
                         const float* __restrict__ minD,
                         const float* __restrict__ maxD,
                         float* __restrict__ depths,
                         float* __restrict__ M) {
    int t = threadIdx.x;
    if (t < CV_D) {
        float mn = minD[0], mx = maxD[0];
        float ramp = (float)t * (1.0f / (CV_D - 1));
        depths[t] = expf(logf(mn) + logf(mx / mn) * ramp);
    }
    if (t < CV_K) {
        const float* Km = Ks + t * 16;
        const float* E  = extr + t * 16;
        float P[3][4];
        for (int i = 0; i < 3; ++i)
            for (int j = 0; j < 4; ++j) {
                float s = 0.f;
                for (int l = 0; l < 4; ++l) s += Km[i * 4 + l] * E[l * 4 + j];
                P[i][j] = s;
            }
        float* Mk = M + t * 12;
        for (int i = 0; i < 3; ++i)
            for (int j = 0; j < 3; ++j) {
                float s = 0.f;
                for (int l = 0; l < 3; ++l) s += P[i][l] * invK[l * 4 + j];
                Mk[i * 3 + j] = s;
            }
        for (int i = 0; i < 3; ++i) Mk[9 + i] = P[i][3];
    }
}

// ---------------------------------------------------------------------------
// [G,C,H,W] -> [G,H,W,C]  (G = K for src_feats, 1 for cur_feats)
// dst index == tid (c innermost); src gathered at channel stride H*W.
// Writes fully coalesced; reads L2-resident (total 11 MB r+w, trivial).
// ---------------------------------------------------------------------------
__global__ void cv_transpose(const float* __restrict__ src,
                             float* __restrict__ dst, int n) {
    int tid = blockIdx.x * blockDim.x + threadIdx.x;
    if (tid >= n) return;
    int c    = tid & (CV_C - 1);
    int rest = tid >> 4;            // g*H*W + h*W + w
    int w    = rest & (CV_W - 1);
    int gh   = rest >> 7;
    int h    = gh % CV_H;
    int g    = gh / CV_H;
    dst[tid] = src[((g * CV_C + c) * CV_H + h) * CV_W + w];
}

__device__ __forceinline__ float dot16(const float* __restrict__ p,
                                       float4 c0, float4 c1, float4 c2, float4 c3) {
    const float4* f = (const float4*)p;
    float4 a = f[0], b = f[1], c = f[2], d = f[3];
    return a.x * c0.x + a.y * c0.y + a.z * c0.z + a.w * c0.w +
           b.x * c1.x + b.y * c1.y + b.z * c1.z + b.w * c1.w +
           c.x * c2.x + c.y * c2.y + c.z * c2.z + c.w * c2.w +
           d.x * c3.x + d.y * c3.y + d.z * c3.z + d.w * c3.w;
}

// ---------------------------------------------------------------------------
// Main: one thread per output element (d,h,w).  48 blocks per depth plane
// (d uniform per block -> depth & matrices via scalar loads).  Loops over
// K=7 views: project, bilinear 4-corner gather (4x float4 each, [H,W,C]
// layout), dot with register-resident cur features, masked accumulate.
// ---------------------------------------------------------------------------
__global__ __launch_bounds__(256) void cv_main(
    const float* __restrict__ srcT,    // [K,H,W,C]
    const float* __restrict__ curT,    // [H,W,C]
    const float* __restrict__ depths,  // [D]
    const float* __restrict__ M,       // [K,12]
    float* __restrict__ out) {         // [D,H,W]
    const int d  = blockIdx.x / (CV_H * CV_W / 256);   // 48 blocks per d
    const int b2 = blockIdx.x % (CV_H * CV_W / 256);
    const int h  = b2 * 2 + (threadIdx.x >> 7);
    const int w  = threadIdx.x & (CV_W - 1);

    const float px = w + 0.5f;
    const float py = h + 0.5f;
    const float depth = depths[d];

    const float* cf = curT + (h * CV_W + w) * CV_C;
    const float4* cfv = (const float4*)cf;
    const float4 c0 = cfv[0], c1 = cfv[1], c2 = cfv[2], c3 = cfv[3];

    float acc = 0.f;
    for (int k = 0; k < CV_K; ++k) {
        const float* Mk = M + k * 12;
        float qx = Mk[0] * px + Mk[1] * py + Mk[2];
        float qy = Mk[3] * px + Mk[4] * py + Mk[5];
        float qz = Mk[6] * px + Mk[7] * py + Mk[8];
        float cx = depth * qx + Mk[9];
        float cy = depth * qy + Mk[10];
        float cz = depth * qz + Mk[11];
        if (cz > 0.f) {                      // z>0 mask (skip == multiply by 0)
            float inv = 1.0f / (cz + CV_EPS);
            float x = cx * inv - 0.5f;
            float y = cy * inv - 0.5f;
            float xf = floorf(x), yf = floorf(y);
            float wx1 = x - xf, wy1 = y - yf;
            float wx0 = 1.f - wx1, wy0 = 1.f - wy1;
            int x0 = (int)xf, y0 = (int)yf;
            int x1 = x0 + 1, y1 = y0 + 1;
            bool vx0 = (unsigned)x0 < (unsigned)CV_W;
            bool vx1 = (unsigned)x1 < (unsigned)CV_W;
            bool vy0 = (unsigned)y0 < (unsigned)CV_H;
            bool vy1 = (unsigned)y1 < (unsigned)CV_H;
            int cx0 = min(max(x0, 0), CV_W - 1);
            int cx1 = min(max(x1, 0), CV_W - 1);
            int cy0 = min(max(y0, 0), CV_H - 1);
            int cy1 = min(max(y1, 0), CV_H - 1);
            const float* base = srcT + k * (CV_H * CV_W * CV_C);
            const float* r0 = base + cy0 * (CV_W * CV_C);
            const float* r1 = base + cy1 * (CV_W * CV_C);
            float d00 = dot16(r0 + cx0 * CV_C, c0, c1, c2, c3);
            float d10 = dot16(r0 + cx1 * CV_C, c0, c1, c2, c3);
            float d01 = dot16(r1 + cx0 * CV_C, c0, c1, c2, c3);
            float d11 = dot16(r1 + cx1 * CV_C, c0, c1, c2, c3);
            float w00 = (vx0 && vy0) ? wx0 * wy0 : 0.f;
            float w10 = (vx1 && vy0) ? wx1 * wy0 : 0.f;
            float w01 = (vx0 && vy1) ? wx0 * wy1 : 0.f;
            float w11 = (vx1 && vy1) ? wx1 * wy1 : 0.f;
            acc += w00 * d00 + w10 * d10 + w01 * d01 + w11 * d11;
        }
    }
    out[(d * CV_H + h) * CV_W + w] = acc;
}

extern "C" void kernel_launch(void* const* d_in, const int* in_sizes, int n_in,
                              void* d_out, int out_size, void* d_ws, size_t ws_size,
                              hipStream_t stream) {
    const float* cur_feats = (const float*)d_in[0];  // [1,16,96,128]
    const float* src_feats = (const float*)d_in[1];  // [1,7,16,96,128]
    const float* extr      = (const float*)d_in[2];  // [1,7,4,4]
    // d_in[3] = src_poses (unused)
    const float* Ks        = (const float*)d_in[4];  // [1,7,4,4]
    const float* invK      = (const float*)d_in[5];  // [1,4,4]
    const float* minD      = (const float*)d_in[6];
    const float* maxD      = (const float*)d_in[7];
    float* out = (float*)d_out;

    float* ws     = (float*)d_ws;
    float* depths = ws;                                   // 64 floats
    float* M      = ws + 64;                              // 84 floats
    float* curT   = ws + 256;                             // 196608 floats, 64B-aligned
    float* srcT   = ws + 256 + CV_H * CV_W * CV_C;        // 1376256 floats

    cv_setup<<<1, 64, 0, stream>>>(extr, Ks, invK, minD, maxD, depths, M);

    int n_src = CV_K * CV_C * CV_H * CV_W;
    int n_cur = CV_C * CV_H * CV_W;
    cv_transpose<<<(n_src + 255) / 256, 256, 0, stream>>>(src_feats, srcT, n_src);
    cv_transpose<<<(n_cur + 255) / 256, 256, 0, stream>>>(cur_feats, curT, n_cur);

    cv_main<<<CV_D * (CV_H * CV_W / 256), 256, 0, stream>>>(srcT, curT, depths, M, out);
}

// Round 2
// 34.895 us; speedup vs baseline: 3.0203x; 3.0203x over previous
//
#include <hip/hip_runtime.h>

#define CV_H 96
#define CV_W 128
#define CV_C 16
#define CV_K 7
#define CV_D 64
#define CV_EPS 1e-8f
#define CV_HW (CV_H * CV_W)

typedef _Float16 v2h __attribute__((ext_vector_type(2)));
typedef _Float16 v8h __attribute__((ext_vector_type(8)));

#if __has_builtin(__builtin_amdgcn_fdot2)
#define FDOT2(a, b, c) __builtin_amdgcn_fdot2((a), (b), (c), false)
#else
#define FDOT2(a, b, c) ((float)(a)[0] * (float)(b)[0] + (float)(a)[1] * (float)(b)[1] + (c))
#endif

// ---------------------------------------------------------------------------
// Fused prep: (a) block 0 computes depth planes + per-view fused projection
// M[k] = [A|b], A=(Ks@E)[:3,:3]@invK[:3,:3], b=(Ks@E)[:3,3];
// (b) all blocks transpose+convert [G,C,H,W] f32 -> [G,H,W,C] fp16
//     (G=0..6 src views, G=7 cur).
// ---------------------------------------------------------------------------
__global__ __launch_bounds__(256) void cv_prep(
    const float* __restrict__ cur, const float* __restrict__ src,
    const float* __restrict__ extr, const float* __restrict__ Ks,
    const float* __restrict__ invK, const float* __restrict__ minD,
    const float* __restrict__ maxD,
    float* __restrict__ depths, float* __restrict__ M,
    _Float16* __restrict__ srcT, _Float16* __restrict__ curT) {
    if (blockIdx.x == 0) {
        int t = threadIdx.x;
        if (t < CV_D) {
            float mn = minD[0], mx = maxD[0];
            float ramp = (float)t * (1.0f / (CV_D - 1));
            depths[t] = expf(logf(mn) + logf(mx / mn) * ramp);
        }
        if (t < CV_K) {
            const float* Km = Ks + t * 16;
            const float* E  = extr + t * 16;
            float P[3][4];
            for (int i = 0; i < 3; ++i)
                for (int j = 0; j < 4; ++j) {
                    float s = 0.f;
                    for (int l = 0; l < 4; ++l) s += Km[i * 4 + l] * E[l * 4 + j];
                    P[i][j] = s;
                }
            float* Mk = M + t * 12;
            for (int i = 0; i < 3; ++i)
                for (int j = 0; j < 3; ++j) {
                    float s = 0.f;
                    for (int l = 0; l < 3; ++l) s += P[i][l] * invK[l * 4 + j];
                    Mk[i * 3 + j] = s;
                }
            for (int i = 0; i < 3; ++i) Mk[9 + i] = P[i][3];
        }
    }
    int tid = blockIdx.x * 256 + threadIdx.x;
    int c    = tid & (CV_C - 1);
    int rest = tid >> 4;            // g*H*W + h*W + w
    int w    = rest & (CV_W - 1);
    int gh   = rest >> 7;
    int h    = gh % CV_H;
    int g    = gh / CV_H;
    if (g < CV_K) {
        srcT[tid] = (_Float16)src[((g * CV_C + c) * CV_H + h) * CV_W + w];
    } else {
        curT[tid - CV_K * CV_HW * CV_C] = (_Float16)cur[(c * CV_H + h) * CV_W + w];
    }
}

__device__ __forceinline__ float dot16h(v8h a0, v8h a1, v8h b0, v8h b1) {
    const v2h* pa0 = (const v2h*)&a0; const v2h* pb0 = (const v2h*)&b0;
    const v2h* pa1 = (const v2h*)&a1; const v2h* pb1 = (const v2h*)&b1;
    float s = 0.f;
#pragma unroll
    for (int i = 0; i < 4; ++i) s = FDOT2(pa0[i], pb0[i], s);
#pragma unroll
    for (int i = 0; i < 4; ++i) s = FDOT2(pa1[i], pb1[i], s);
    return s;
}

// ---------------------------------------------------------------------------
// Main: one thread per output element.  Block = 8w x 8h spatial tile x 4
// adjacent depths (wave 0 = full 8x8 tile at one depth -> tight L1 window;
// adjacent depths sample within a few px for this pose distribution).
// Per view: project, 4-corner bilinear gather (2x b128 fp16 loads per
// corner), fdot2 with register-resident cur features, masked accumulate.
// ---------------------------------------------------------------------------
__global__ __launch_bounds__(256) void cv_main(
    const _Float16* __restrict__ srcT,   // [K,H,W,C] fp16
    const _Float16* __restrict__ curT,   // [H,W,C]   fp16
    const float* __restrict__ depths,    // [D]
    const float* __restrict__ Mg,        // [K,12]
    float* __restrict__ out) {           // [D,H,W]
    const int bx = blockIdx.x;
    const int wb = bx & 15;              // 16 w-blocks
    const int hb = (bx >> 4) % 12;       // 12 h-blocks
    const int db = bx / 192;             // 16 d-blocks
    const int wx = threadIdx.x & 7;
    const int hy = (threadIdx.x >> 3) & 7;
    const int dd = threadIdx.x >> 6;
    const int w = wb * 8 + wx;
    const int h = hb * 8 + hy;
    const int d = db * 4 + dd;

    const float px = w + 0.5f;
    const float py = h + 0.5f;
    const float depth = depths[d];

    const v8h* cp = (const v8h*)(curT + (h * CV_W + w) * CV_C);
    const v8h c0 = cp[0], c1 = cp[1];

    float acc = 0.f;
#pragma unroll
    for (int k = 0; k < CV_K; ++k) {
        const float* Mk = Mg + k * 12;
        float qx = Mk[0] * px + Mk[1] * py + Mk[2];
        float qy = Mk[3] * px + Mk[4] * py + Mk[5];
        float qz = Mk[6] * px + Mk[7] * py + Mk[8];
        float cx = depth * qx + Mk[9];
        float cy = depth * qy + Mk[10];
        float cz = depth * qz + Mk[11];
        if (cz > 0.f) {                  // z>0 mask
            float inv = 1.0f / (cz + CV_EPS);
            float x = cx * inv - 0.5f;
            float y = cy * inv - 0.5f;
            float xf = floorf(x), yf = floorf(y);
            float wx1 = x - xf, wy1 = y - yf;
            float wx0 = 1.f - wx1, wy0 = 1.f - wy1;
            int x0 = (int)xf, y0 = (int)yf;
            int x1 = x0 + 1, y1 = y0 + 1;
            bool vx0 = (unsigned)x0 < (unsigned)CV_W;
            bool vx1 = (unsigned)x1 < (unsigned)CV_W;
            bool vy0 = (unsigned)y0 < (unsigned)CV_H;
            bool vy1 = (unsigned)y1 < (unsigned)CV_H;
            int cx0 = min(max(x0, 0), CV_W - 1);
            int cx1 = min(max(x1, 0), CV_W - 1);
            int cy0 = min(max(y0, 0), CV_H - 1);
            int cy1 = min(max(y1, 0), CV_H - 1);
            const v8h* base = (const v8h*)srcT + (size_t)k * (CV_HW * 2);
            const v8h* r0 = base + cy0 * (CV_W * 2);
            const v8h* r1 = base + cy1 * (CV_W * 2);
            // issue all 8 loads, then reduce (MLP)
            v8h a00 = r0[cx0 * 2], b00 = r0[cx0 * 2 + 1];
            v8h a10 = r0[cx1 * 2], b10 = r0[cx1 * 2 + 1];
            v8h a01 = r1[cx0 * 2], b01 = r1[cx0 * 2 + 1];
            v8h a11 = r1[cx1 * 2], b11 = r1[cx1 * 2 + 1];
            float w00 = (vx0 && vy0) ? wx0 * wy0 : 0.f;
            float w10 = (vx1 && vy0) ? wx1 * wy0 : 0.f;
            float w01 = (vx0 && vy1) ? wx0 * wy1 : 0.f;
            float w11 = (vx1 && vy1) ? wx1 * wy1 : 0.f;
            acc += w00 * dot16h(a00, b00, c0, c1)
                 + w10 * dot16h(a10, b10, c0, c1)
                 + w01 * dot16h(a01, b01, c0, c1)
                 + w11 * dot16h(a11, b11, c0, c1);
        }
    }
    out[(d * CV_H + h) * CV_W + w] = acc;
}

extern "C" void kernel_launch(void* const* d_in, const int* in_sizes, int n_in,
                              void* d_out, int out_size, void* d_ws, size_t ws_size,
                              hipStream_t stream) {
    const float* cur_feats = (const float*)d_in[0];  // [1,16,96,128]
    const float* src_feats = (const float*)d_in[1];  // [1,7,16,96,128]
    const float* extr      = (const float*)d_in[2];  // [1,7,4,4]
    // d_in[3] = src_poses (unused)
    const float* Ks        = (const float*)d_in[4];  // [1,7,4,4]
    const float* invK      = (const float*)d_in[5];  // [1,4,4]
    const float* minD      = (const float*)d_in[6];
    const float* maxD      = (const float*)d_in[7];
    float* out = (float*)d_out;

    float* wsf    = (float*)d_ws;
    float* depths = wsf;                       // 64 floats
    float* M      = wsf + 64;                  // 84 floats
    _Float16* srcT = (_Float16*)(wsf + 256);   // [7,96,128,16] fp16 (1 KB-aligned)
    _Float16* curT = srcT + CV_K * CV_HW * CV_C;

    int n_total = (CV_K + 1) * CV_C * CV_HW;   // 1,572,864
    cv_prep<<<n_total / 256, 256, 0, stream>>>(cur_feats, src_feats, extr, Ks,
                                               invK, minD, maxD, depths, M,
                                               srcT, curT);

    cv_main<<<CV_D / 4 * (CV_H / 8) * (CV_W / 8), 256, 0, stream>>>(
        srcT, curT, depths, M, out);
}

// Round 3
// 34.304 us; speedup vs baseline: 3.0723x; 1.0172x over previous
//
#include <hip/hip_runtime.h>

#define CV_H 96
#define CV_W 128
#define CV_C 16
#define CV_K 7
#define CV_D 64
#define CV_EPS 1e-8f
#define CV_HW (CV_H * CV_W)

typedef _Float16 v2h __attribute__((ext_vector_type(2)));
typedef _Float16 v8h __attribute__((ext_vector_type(8)));

#if __has_builtin(__builtin_amdgcn_fdot2)
#define FDOT2(a, b, c) __builtin_amdgcn_fdot2((a), (b), (c), false)
#else
#define FDOT2(a, b, c) ((float)(a)[0] * (float)(b)[0] + (float)(a)[1] * (float)(b)[1] + (c))
#endif

// ---------------------------------------------------------------------------
// Fused prep.  Blocks 0..(K+1)*H-1: LDS-tiled transpose+convert of one
// (view,row): [C=16][W=128] f32 (coalesced float4 reads) -> [W][C] fp16
// (coalesced v8h writes).  Last block: depth planes + fused projection
// matrices M[k]=[A|b], A=(Ks@E)[:3,:3]@invK[:3,:3], b=(Ks@E)[:3,3];
// cam = depth*(A@[x+.5,y+.5,1]) + b.
// ---------------------------------------------------------------------------
__global__ __launch_bounds__(256) void cv_prep(
    const float* __restrict__ cur, const float* __restrict__ src,
    const float* __restrict__ extr, const float* __restrict__ Ks,
    const float* __restrict__ invK, const float* __restrict__ minD,
    const float* __restrict__ maxD,
    float* __restrict__ depths, float* __restrict__ M,
    _Float16* __restrict__ srcT, _Float16* __restrict__ curT) {
    const int b = blockIdx.x;
    if (b == (CV_K + 1) * CV_H) {            // tiny setup block
        int t = threadIdx.x;
        if (t < CV_D) {
            float mn = minD[0], mx = maxD[0];
            float ramp = (float)t * (1.0f / (CV_D - 1));
            depths[t] = expf(logf(mn) + logf(mx / mn) * ramp);
        }
        if (t < CV_K) {
            const float* Km = Ks + t * 16;
            const float* E  = extr + t * 16;
            float P[3][4];
            for (int i = 0; i < 3; ++i)
                for (int j = 0; j < 4; ++j) {
                    float s = 0.f;
                    for (int l = 0; l < 4; ++l) s += Km[i * 4 + l] * E[l * 4 + j];
                    P[i][j] = s;
                }
            float* Mk = M + t * 12;
            for (int i = 0; i < 3; ++i)
                for (int j = 0; j < 3; ++j) {
                    float s = 0.f;
                    for (int l = 0; l < 3; ++l) s += P[i][l] * invK[l * 4 + j];
                    Mk[i * 3 + j] = s;
                }
            for (int i = 0; i < 3; ++i) Mk[9 + i] = P[i][3];
        }
        return;
    }
    const int g = b / CV_H;                  // 0..6 src views, 7 = cur
    const int h = b % CV_H;
    const float* rowBase = (g < CV_K) ? (src + (size_t)g * CV_C * CV_HW + h * CV_W)
                                      : (cur + h * CV_W);
    __shared__ float lds[CV_C][CV_W + 2];
    const int t = threadIdx.x;
#pragma unroll
    for (int i = 0; i < 2; ++i) {
        int f  = t + i * 256;                // float4 id, 0..511
        int c  = f >> 5;
        int w4 = (f & 31) << 2;
        float4 v = *(const float4*)(rowBase + (size_t)c * CV_HW + w4);
        lds[c][w4 + 0] = v.x; lds[c][w4 + 1] = v.y;
        lds[c][w4 + 2] = v.z; lds[c][w4 + 3] = v.w;
    }
    __syncthreads();
    const int p  = t >> 1;                   // pixel 0..127
    const int cb = (t & 1) << 3;             // channel half 0 / 8
    v8h o;
#pragma unroll
    for (int j = 0; j < 8; ++j) o[j] = (_Float16)lds[cb + j][p];
    _Float16* dst = (g < CV_K)
        ? (srcT + ((size_t)g * CV_HW + h * CV_W + p) * CV_C + cb)
        : (curT + ((size_t)h * CV_W + p) * CV_C + cb);
    *(v8h*)dst = o;
}

__device__ __forceinline__ float dot16h(v8h a0, v8h a1, v8h b0, v8h b1) {
    const v2h* pa0 = (const v2h*)&a0; const v2h* pb0 = (const v2h*)&b0;
    const v2h* pa1 = (const v2h*)&a1; const v2h* pb1 = (const v2h*)&b1;
    float s = 0.f;
#pragma unroll
    for (int i = 0; i < 4; ++i) s = FDOT2(pa0[i], pb0[i], s);
#pragma unroll
    for (int i = 0; i < 4; ++i) s = FDOT2(pa1[i], pb1[i], s);
    return s;
}

// ---------------------------------------------------------------------------
// Main: one thread per output element; block = 8w x 8h x 4 adjacent depths.
// BRANCHLESS 7-view loop (z-mask folded into weights, coords clamped so all
// address math is always safe) so the compiler can software-pipeline the
// 8 gather loads per view across views.
// ---------------------------------------------------------------------------
__global__ __launch_bounds__(256, 4) void cv_main(
    const _Float16* __restrict__ srcT,   // [K,H,W,C] fp16
    const _Float16* __restrict__ curT,   // [H,W,C]   fp16
    const float* __restrict__ depths,    // [D]
    const float* __restrict__ Mg,        // [K,12]
    float* __restrict__ out) {           // [D,H,W]
    const int bx = blockIdx.x;
    const int wb = bx & 15;
    const int hb = (bx >> 4) % 12;
    const int db = bx / 192;
    const int wx = threadIdx.x & 7;
    const int hy = (threadIdx.x >> 3) & 7;
    const int dd = threadIdx.x >> 6;
    const int w = wb * 8 + wx;
    const int h = hb * 8 + hy;
    const int d = db * 4 + dd;

    const float px = w + 0.5f;
    const float py = h + 0.5f;
    const float depth = depths[d];

    const v8h* cp = (const v8h*)(curT + (h * CV_W + w) * CV_C);
    const v8h c0 = cp[0], c1 = cp[1];

    float acc = 0.f;
#pragma unroll
    for (int k = 0; k < CV_K; ++k) {
        const float* Mk = Mg + k * 12;
        float qx = Mk[0] * px + Mk[1] * py + Mk[2];
        float qy = Mk[3] * px + Mk[4] * py + Mk[5];
        float qz = Mk[6] * px + Mk[7] * py + Mk[8];
        float cx = depth * qx + Mk[9];
        float cy = depth * qy + Mk[10];
        float cz = depth * qz + Mk[11];
        float valid = (cz > 0.f) ? 1.f : 0.f;            // z>0 mask
        float inv = 1.0f / (fabsf(cz) + CV_EPS);         // == 1/(cz+eps) when cz>0
        float x = fminf(fmaxf(cx * inv - 0.5f, -4.0f), (float)(CV_W + 3));
        float y = fminf(fmaxf(cy * inv - 0.5f, -4.0f), (float)(CV_H + 3));
        float xf = floorf(x), yf = floorf(y);
        float wx1 = x - xf, wy1 = y - yf;
        float wx0 = 1.f - wx1, wy0 = 1.f - wy1;
        int x0 = (int)xf, y0 = (int)yf;
        int x1 = x0 + 1, y1 = y0 + 1;
        bool vx0 = (unsigned)x0 < (unsigned)CV_W;
        bool vx1 = (unsigned)x1 < (unsigned)CV_W;
        bool vy0 = (unsigned)y0 < (unsigned)CV_H;
        bool vy1 = (unsigned)y1 < (unsigned)CV_H;
        int cx0 = min(max(x0, 0), CV_W - 1);
        int cx1 = min(max(x1, 0), CV_W - 1);
        int cy0 = min(max(y0, 0), CV_H - 1);
        int cy1 = min(max(y1, 0), CV_H - 1);
        const v8h* base = (const v8h*)srcT + (size_t)k * (CV_HW * 2);
        const v8h* r0 = base + cy0 * (CV_W * 2);
        const v8h* r1 = base + cy1 * (CV_W * 2);
        v8h a00 = r0[cx0 * 2], b00 = r0[cx0 * 2 + 1];
        v8h a10 = r0[cx1 * 2], b10 = r0[cx1 * 2 + 1];
        v8h a01 = r1[cx0 * 2], b01 = r1[cx0 * 2 + 1];
        v8h a11 = r1[cx1 * 2], b11 = r1[cx1 * 2 + 1];
        float w00 = (vx0 && vy0) ? wx0 * wy0 : 0.f;
        float w10 = (vx1 && vy0) ? wx1 * wy0 : 0.f;
        float w01 = (vx0 && vy1) ? wx0 * wy1 : 0.f;
        float w11 = (vx1 && vy1) ? wx1 * wy1 : 0.f;
        float s = w00 * dot16h(a00, b00, c0, c1)
                + w10 * dot16h(a10, b10, c0, c1)
                + w01 * dot16h(a01, b01, c0, c1)
                + w11 * dot16h(a11, b11, c0, c1);
        acc = fmaf(valid, s, acc);
    }
    out[(d * CV_H + h) * CV_W + w] = acc;
}

extern "C" void kernel_launch(void* const* d_in, const int* in_sizes, int n_in,
                              void* d_out, int out_size, void* d_ws, size_t ws_size,
                              hipStream_t stream) {
    const float* cur_feats = (const float*)d_in[0];  // [1,16,96,128]
    const float* src_feats = (const float*)d_in[1];  // [1,7,16,96,128]
    const float* extr      = (const float*)d_in[2];  // [1,7,4,4]
    // d_in[3] = src_poses (unused)
    const float* Ks        = (const float*)d_in[4];  // [1,7,4,4]
    const float* invK      = (const float*)d_in[5];  // [1,4,4]
    const float* minD      = (const float*)d_in[6];
    const float* maxD      = (const float*)d_in[7];
    float* out = (float*)d_out;

    float* wsf    = (float*)d_ws;
    float* depths = wsf;                       // 64 floats
    float* M      = wsf + 64;                  // 84 floats
    _Float16* srcT = (_Float16*)(wsf + 256);   // [7,96,128,16] fp16
    _Float16* curT = srcT + CV_K * CV_HW * CV_C;

    cv_prep<<<(CV_K + 1) * CV_H + 1, 256, 0, stream>>>(
        cur_feats, src_feats, extr, Ks, invK, minD, maxD, depths, M, srcT, curT);

    cv_main<<<CV_D / 4 * (CV_H / 8) * (CV_W / 8), 256, 0, stream>>>(
        srcT, curT, depths, M, out);
}